// Round 4
// baseline (641.670 us; speedup 1.0000x reference)
//
#include <hip/hip_runtime.h>
#include <hip/hip_bf16.h>

#define CH 8
#define SEC 32768
#define FIN 64
#define FOUT 64
#define UN 512
#define BM 128

typedef __bf16 bf16;
typedef bf16 bf16x8 __attribute__((ext_vector_type(8)));
typedef bf16 bf16x4 __attribute__((ext_vector_type(4)));
typedef float f32x4 __attribute__((ext_vector_type(4)));

// load 8 consecutive fp32 and convert to bf16x8 (register path)
__device__ __forceinline__ bf16x8 cvt8(const float* __restrict__ src) {
  f32x4 u0 = *(const f32x4*)src;
  f32x4 u1 = *(const f32x4*)(src + 4);
  bf16x8 v;
  v[0] = (bf16)u0[0]; v[1] = (bf16)u0[1]; v[2] = (bf16)u0[2]; v[3] = (bf16)u0[3];
  v[4] = (bf16)u1[0]; v[5] = (bf16)u1[1]; v[6] = (bf16)u1[2]; v[7] = (bf16)u1[3];
  return v;
}

__device__ __forceinline__ void store_cvt8(void* dst, const float* __restrict__ src) {
  *(bf16x8*)dst = cvt8(src);
}

// ---------------------------------------------------------------------------
// Main layer: act [128 x K] (LDS, frag order [8 mt][NKS][64 lanes][16B])
//  x W[512 x K]^T -> [128 x 512], bias+relu, in-place back into act.
// 16 waves: wm = w>>3 (row group of 64), wn = w&7 (col group of 64).
// B-fragments: direct global->reg, explicit double-buffer (B0/B1), statically
// alternated by unroll-2 -> loads for kstep j+1 fly during MFMAs of kstep j.
// K-step rotation per block decorrelates same-line L2 reads across blocks.
// ---------------------------------------------------------------------------
template<int K, bool WSPATH>
__device__ __forceinline__ void run_main_layer(
    const bf16* __restrict__ wb, const float* __restrict__ wf,
    const float* __restrict__ bias, char* __restrict__ act,
    int w, int l, int l15, int l4, int wm, int wn, int rot)
{
  constexpr int NKS = K / 32;
  constexpr int MASK = NKS - 1;
  const char* abase = act + wm * (4 * NKS * 1024) + l * 16;

  const bf16*  bp[4];
  const float* bpf[4];
#pragma unroll
  for (int nt = 0; nt < 4; ++nt) {
    const int col = wn * 64 + nt * 16 + l15;
    if constexpr (WSPATH) bp[nt]  = wb + (size_t)col * K + l4 * 8;
    else                  bpf[nt] = wf + (size_t)col * K + l4 * 8;
  }

  f32x4 acc[4][4];
#pragma unroll
  for (int mt = 0; mt < 4; ++mt)
#pragma unroll
    for (int nt = 0; nt < 4; ++nt)
      acc[mt][nt] = f32x4{0.f, 0.f, 0.f, 0.f};

  if constexpr (WSPATH) {
    bf16x8 B0[4], B1[4];
    {
      const int ks = rot & MASK;
#pragma unroll
      for (int nt = 0; nt < 4; ++nt) B0[nt] = *(const bf16x8*)(bp[nt] + ks * 32);
    }
#pragma unroll
    for (int j = 0; j < NKS; j += 2) {
      {
        const int ksn = (j + 1 + rot) & MASK;
#pragma unroll
        for (int nt = 0; nt < 4; ++nt) B1[nt] = *(const bf16x8*)(bp[nt] + ksn * 32);
        const int ks = (j + rot) & MASK;
        bf16x8 a[4];
#pragma unroll
        for (int mt = 0; mt < 4; ++mt)
          a[mt] = *(const bf16x8*)(abase + mt * (NKS * 1024) + ks * 1024);
        __builtin_amdgcn_s_setprio(1);
#pragma unroll
        for (int mt = 0; mt < 4; ++mt)
#pragma unroll
          for (int nt = 0; nt < 4; ++nt)
            acc[mt][nt] = __builtin_amdgcn_mfma_f32_16x16x32_bf16(a[mt], B0[nt], acc[mt][nt], 0, 0, 0);
        __builtin_amdgcn_s_setprio(0);
      }
      {
        if (j + 2 < NKS) {
          const int ksn = (j + 2 + rot) & MASK;
#pragma unroll
          for (int nt = 0; nt < 4; ++nt) B0[nt] = *(const bf16x8*)(bp[nt] + ksn * 32);
        }
        const int ks = (j + 1 + rot) & MASK;
        bf16x8 a[4];
#pragma unroll
        for (int mt = 0; mt < 4; ++mt)
          a[mt] = *(const bf16x8*)(abase + mt * (NKS * 1024) + ks * 1024);
        __builtin_amdgcn_s_setprio(1);
#pragma unroll
        for (int mt = 0; mt < 4; ++mt)
#pragma unroll
          for (int nt = 0; nt < 4; ++nt)
            acc[mt][nt] = __builtin_amdgcn_mfma_f32_16x16x32_bf16(a[mt], B1[nt], acc[mt][nt], 0, 0, 0);
        __builtin_amdgcn_s_setprio(0);
      }
    }
  } else {
    // fallback (no bf16 workspace): simple per-kstep convert, no prefetch
    for (int j = 0; j < NKS; ++j) {
      const int ks = (j + rot) & MASK;
      bf16x8 a[4], b[4];
#pragma unroll
      for (int nt = 0; nt < 4; ++nt) b[nt] = cvt8(bpf[nt] + ks * 32);
#pragma unroll
      for (int mt = 0; mt < 4; ++mt)
        a[mt] = *(const bf16x8*)(abase + mt * (NKS * 1024) + ks * 1024);
#pragma unroll
      for (int mt = 0; mt < 4; ++mt)
#pragma unroll
        for (int nt = 0; nt < 4; ++nt)
          acc[mt][nt] = __builtin_amdgcn_mfma_f32_16x16x32_bf16(a[mt], b[nt], acc[mt][nt], 0, 0, 0);
    }
  }

  __syncthreads();  // all reads of act done

  // epilogue: bias+relu -> act in next layer's frag order ([8 mt][16 ks][1024])
#pragma unroll
  for (int nt = 0; nt < 4; ++nt) {
    const int col = wn * 64 + nt * 16 + l15;   // = next layer's k index
    const float bv = bias[col];
    const int coff = (col >> 5) * 1024 + ((col >> 3) & 3) * 256 + (col & 7) * 2 + l4 * 64;
#pragma unroll
    for (int mt = 0; mt < 4; ++mt) {
      const int base = (wm * 4 + mt) * 16384 + coff;
#pragma unroll
      for (int r = 0; r < 4; ++r) {
        float v = acc[mt][nt][r] + bv;
        v = v > 0.f ? v : 0.f;
        *(bf16*)(act + base + r * 16) = (bf16)v;
      }
    }
  }
  __syncthreads();  // act ready for next layer
}

// ---------------------------------------------------------------------------
// Final layer: [128 x 512] x [64 x 512]^T -> [128 x 64] fp32, no relu.
// 16 waves: rg = w>>2 (row group of 32 -> 2 mtiles), cg = w&3 (col frag).
// ---------------------------------------------------------------------------
template<bool WSPATH>
__device__ __forceinline__ void run_final_layer(
    const bf16* __restrict__ wb, const float* __restrict__ wf,
    const float* __restrict__ bias, const char* __restrict__ act,
    float* __restrict__ gout,
    int w, int l, int l15, int l4, int rot)
{
  constexpr int NKS = 16;
  const int rg = w >> 2, cg = w & 3;
  const char* abase = act + rg * 32768 + l * 16;  // offsets (i*16+ks)*1024 <= 31744

  const bf16*  bp  = nullptr;
  const float* bpf = nullptr;
  if constexpr (WSPATH) bp  = wb + (size_t)(cg * 16 + l15) * UN + l4 * 8;
  else                  bpf = wf + (size_t)(cg * 16 + l15) * UN + l4 * 8;

  f32x4 acc[2];
  acc[0] = f32x4{0.f, 0.f, 0.f, 0.f};
  acc[1] = f32x4{0.f, 0.f, 0.f, 0.f};

  if constexpr (WSPATH) {
    bf16x8 B0 = *(const bf16x8*)(bp + (rot & 15) * 32), B1;
#pragma unroll
    for (int j = 0; j < NKS; j += 2) {
      {
        const int ksn = (j + 1 + rot) & 15;
        B1 = *(const bf16x8*)(bp + ksn * 32);
        const int ks = (j + rot) & 15;
        const bf16x8 a0 = *(const bf16x8*)(abase + ks * 1024);
        const bf16x8 a1 = *(const bf16x8*)(abase + 16384 + ks * 1024);
        acc[0] = __builtin_amdgcn_mfma_f32_16x16x32_bf16(a0, B0, acc[0], 0, 0, 0);
        acc[1] = __builtin_amdgcn_mfma_f32_16x16x32_bf16(a1, B0, acc[1], 0, 0, 0);
      }
      {
        if (j + 2 < NKS) B0 = *(const bf16x8*)(bp + (((j + 2 + rot) & 15)) * 32);
        const int ks = (j + 1 + rot) & 15;
        const bf16x8 a0 = *(const bf16x8*)(abase + ks * 1024);
        const bf16x8 a1 = *(const bf16x8*)(abase + 16384 + ks * 1024);
        acc[0] = __builtin_amdgcn_mfma_f32_16x16x32_bf16(a0, B1, acc[0], 0, 0, 0);
        acc[1] = __builtin_amdgcn_mfma_f32_16x16x32_bf16(a1, B1, acc[1], 0, 0, 0);
      }
    }
  } else {
    for (int j = 0; j < NKS; ++j) {
      const int ks = (j + rot) & 15;
      const bf16x8 b = cvt8(bpf + ks * 32);
      const bf16x8 a0 = *(const bf16x8*)(abase + ks * 1024);
      const bf16x8 a1 = *(const bf16x8*)(abase + 16384 + ks * 1024);
      acc[0] = __builtin_amdgcn_mfma_f32_16x16x32_bf16(a0, b, acc[0], 0, 0, 0);
      acc[1] = __builtin_amdgcn_mfma_f32_16x16x32_bf16(a1, b, acc[1], 0, 0, 0);
    }
  }

  const float bv = bias[cg * 16 + l15];
#pragma unroll
  for (int i = 0; i < 2; ++i) {
#pragma unroll
    for (int r = 0; r < 4; ++r)
      gout[(size_t)(rg * 32 + i * 16 + l4 * 4 + r) * FOUT + cg * 16 + l15] = acc[i][r] + bv;
  }
}

template<bool WSPATH>
__global__ __launch_bounds__(1024, 4) void mlp_fused(
    const float* __restrict__ x,
    const float* __restrict__ w0f, const float* __restrict__ w1f,
    const float* __restrict__ w2f, const float* __restrict__ w3f,
    const float* __restrict__ b0, const float* __restrict__ b1,
    const float* __restrict__ b2, const float* __restrict__ b3,
    const bf16* __restrict__ wbase,
    float* __restrict__ out)
{
  extern __shared__ char smem[];
  char* act = smem;  // 128 KiB in-place activations, frag order

  const int tid = threadIdx.x;
  const int w = tid >> 6, l = tid & 63;
  const int l15 = l & 15, l4 = l >> 4;
  const int wm = w >> 3, wn = w & 7;

  // XCD-chunked swizzle (2048 % 8 == 0 -> bijective): each XCD owns one channel
  const int wg = (blockIdx.x & 7) * 256 + (blockIdx.x >> 3);
  const int ch = wg >> 8;
  const int row0 = (wg & 255) * BM;
  const int rot = wg & 15;  // kstep rotation: co-resident blocks read different lines

  const bf16* w0b = wbase + (size_t)ch * UN * FIN;
  const bf16* w1b = wbase + CH * UN * FIN + (size_t)ch * UN * UN;
  const bf16* w2b = wbase + CH * UN * FIN + CH * UN * UN + (size_t)ch * UN * UN;
  const bf16* w3b = wbase + CH * UN * FIN + 2 * CH * UN * UN + (size_t)ch * FOUT * UN;
  const float* w0c = w0f + (size_t)ch * UN * FIN;
  const float* w1c = w1f + (size_t)ch * UN * UN;
  const float* w2c = w2f + (size_t)ch * UN * UN;
  const float* w3c = w3f + (size_t)ch * FOUT * UN;
  const float* b0c = b0 + ch * UN;
  const float* b1c = b1 + ch * UN;
  const float* b2c = b2 + ch * UN;
  const float* b3c = b3 + ch * FOUT;

  // stage x tile (128 x 64 fp32 -> bf16) into act, frag order [8 mt][2 ks][1024]
  {
    const float* xs = x + (size_t)(ch * SEC + row0) * FIN;
    store_cvt8(act + w * 1024 + l * 16,
               xs + ((w >> 1) * 16 + l15) * FIN + (w & 1) * 32 + l4 * 8);
  }
  __syncthreads();

  run_main_layer<64,  WSPATH>(w0b, w0c, b0c, act, w, l, l15, l4, wm, wn, rot);
  run_main_layer<512, WSPATH>(w1b, w1c, b1c, act, w, l, l15, l4, wm, wn, rot);
  run_main_layer<512, WSPATH>(w2b, w2c, b2c, act, w, l, l15, l4, wm, wn, rot);
  run_final_layer<WSPATH>(w3b, w3c, b3c, act,
                          out + (size_t)(ch * SEC + row0) * FOUT,
                          w, l, l15, l4, rot);
}

// one-shot fp32 -> bf16 weight conversion into d_ws (layout: w0|w1|w2|w3 flat)
__global__ void cvt_weights(const float* __restrict__ w0, const float* __restrict__ w1,
                            const float* __restrict__ w2, const float* __restrict__ w3,
                            bf16* __restrict__ o)
{
  const int n0 = CH * UN * FIN;   // 262144
  const int n1 = CH * UN * UN;    // 2097152
  const int total = 2 * n0 + 2 * n1;
  for (int i4 = blockIdx.x * blockDim.x + threadIdx.x; i4 < total / 4;
       i4 += gridDim.x * blockDim.x) {
    const int idx = i4 * 4;
    const float* src; int off;
    if (idx < n0)                { src = w0; off = idx; }
    else if (idx < n0 + n1)      { src = w1; off = idx - n0; }
    else if (idx < n0 + 2 * n1)  { src = w2; off = idx - n0 - n1; }
    else                         { src = w3; off = idx - n0 - 2 * n1; }
    const f32x4 v = *(const f32x4*)(src + off);
    bf16x4 r;
    r[0] = (bf16)v[0]; r[1] = (bf16)v[1]; r[2] = (bf16)v[2]; r[3] = (bf16)v[3];
    *(bf16x4*)(o + idx) = r;
  }
}

extern "C" void kernel_launch(void* const* d_in, const int* in_sizes, int n_in,
                              void* d_out, int out_size, void* d_ws, size_t ws_size,
                              hipStream_t stream)
{
  const float* x  = (const float*)d_in[0];
  const float* w0 = (const float*)d_in[1];
  const float* w1 = (const float*)d_in[2];
  const float* w2 = (const float*)d_in[3];
  const float* w3 = (const float*)d_in[4];
  const float* b0 = (const float*)d_in[5];
  const float* b1 = (const float*)d_in[6];
  const float* b2 = (const float*)d_in[7];
  const float* b3 = (const float*)d_in[8];
  float* out = (float*)d_out;

  const int grid = CH * (SEC / BM);            // 2048 blocks
  const size_t wbytes = (size_t)(2 * CH * UN * FIN + 2 * CH * UN * UN) * 2;  // 9437184

  if (ws_size >= wbytes) {
    bf16* wb = (bf16*)d_ws;
    hipLaunchKernelGGL(cvt_weights, dim3(2048), dim3(256), 0, stream, w0, w1, w2, w3, wb);
    hipFuncSetAttribute(reinterpret_cast<const void*>(mlp_fused<true>),
                        hipFuncAttributeMaxDynamicSharedMemorySize, 131072);
    hipLaunchKernelGGL(mlp_fused<true>, dim3(grid), dim3(1024), 131072, stream,
                       x, w0, w1, w2, w3, b0, b1, b2, b3, wb, out);
  } else {
    hipFuncSetAttribute(reinterpret_cast<const void*>(mlp_fused<false>),
                        hipFuncAttributeMaxDynamicSharedMemorySize, 131072);
    hipLaunchKernelGGL(mlp_fused<false>, dim3(grid), dim3(1024), 131072, stream,
                       x, w0, w1, w2, w3, b0, b1, b2, b3, (const bf16*)nullptr, out);
  }
}